// Round 2
// baseline (482.339 us; speedup 1.0000x reference)
//
#include <hip/hip_runtime.h>

// VQ: inputs (16,64,64,64) f32 BCHW, codebook (1024,64) f32.
// out[0:65536]        = argmin indices as float
// out[65536: +4.19M]  = gathered codebook vectors, BCHW layout
//
// Numerics: the np reference computes d = ||z||^2 + ||e||^2 - 2 z.e in fp32.
// ||z||^2 ~ 64 dominates, so d is quantized to ulp(64) ~ 7.6e-6 while top-2
// gaps ~ 2.3e-3 -> ~0.3% of positions are rounding-determined near-ties.
// We must therefore replicate: (a) znorm BIT-EXACT to numpy's pairwise sum
// (8 accumulators + tree, squares rounded separately -> fp contract OFF),
// (b) the exact op order t = fl(znorm+cnorm); d = fl(t - fl(2*dot)).
// dot/cnorm orders only matter at the 1e-9/1e-12 scale (negligible flips).
#define NUM_K 1024
#define CDIM  64
#define NPOS  65536   // 16*64*64

// ---- kernel 1: codebook squared norms into d_ws (1024 floats) ----
__global__ __launch_bounds__(256) void vq_cnorm_kernel(
    const float* __restrict__ cb, float* __restrict__ cnorm) {
#pragma clang fp contract(off)
    int k = blockIdx.x * 256 + threadIdx.x;   // grid = 4 blocks
    const float* row = cb + k * CDIM;
    // numpy pairwise order for n=64 (errors here are ~1e-12, order-insensitive
    // for the argmin, but replicate anyway since it's free)
    float r[8];
#pragma unroll
    for (int j = 0; j < 8; ++j) r[j] = row[j] * row[j];
#pragma unroll
    for (int i = 1; i < 8; ++i) {
#pragma unroll
        for (int j = 0; j < 8; ++j) {
            float s = row[i * 8 + j] * row[i * 8 + j];
            r[j] = r[j] + s;
        }
    }
    cnorm[k] = ((r[0] + r[1]) + (r[2] + r[3])) + ((r[4] + r[5]) + (r[6] + r[7]));
}

#define FMA4(acc, zb, v)                      \
    acc = fmaf(z[(zb) + 0], v.x, acc);        \
    acc = fmaf(z[(zb) + 1], v.y, acc);        \
    acc = fmaf(z[(zb) + 2], v.z, acc);        \
    acc = fmaf(z[(zb) + 3], v.w, acc);

// ---- kernel 2: main VQ ----
// grid = 1024 blocks x 256 threads. Block g owns 64 consecutive flat
// positions n0 = g*64 (all in the same batch image since 64 | 4096).
// Wave w scans codes [w*256, (w+1)*256); lane l owns position n0+l.
__global__ __launch_bounds__(256, 4) void vq_main_kernel(
    const float* __restrict__ in, const float* __restrict__ cb,
    const float* __restrict__ cnorm, float* __restrict__ out) {
#pragma clang fp contract(off)
    const int tid  = threadIdx.x;
    const int lane = tid & 63;
    const int wid  = tid >> 6;          // 0..3
    const int n0   = blockIdx.x << 6;
    const int b    = n0 >> 12;          // / 4096
    const int hw0  = n0 & 4095;

    // load this lane's z vector (64 channels, stride H*W=4096 floats)
    const float* zp = in + ((b * CDIM) << 12) + hw0 + lane;
    float z[CDIM];
#pragma unroll
    for (int c = 0; c < CDIM; ++c) z[c] = zp[c << 12];

    // znorm: bit-exact numpy pairwise sum of z[c]^2 (squares rounded
    // individually -> contract off; 8 accumulators; tree combine)
    float r[8];
#pragma unroll
    for (int j = 0; j < 8; ++j) r[j] = z[j] * z[j];
#pragma unroll
    for (int i = 1; i < 8; ++i) {
#pragma unroll
        for (int j = 0; j < 8; ++j) {
            float s = z[i * 8 + j] * z[i * 8 + j];
            r[j] = r[j] + s;
        }
    }
    const float znorm =
        ((r[0] + r[1]) + (r[2] + r[3])) + ((r[4] + r[5]) + (r[6] + r[7]));

    const float4* cb4 = reinterpret_cast<const float4*>(cb);
    const int k0 = wid << 8;
    float best  = 3.4e38f;
    int   bestk = 0;
    for (int kk = 0; kk < 256; ++kk) {
        const int k = k0 + kk;
        const float4* e = cb4 + k * (CDIM / 4);
        float a0 = 0.f, a1 = 0.f, a2 = 0.f, a3 = 0.f;
#pragma unroll
        for (int i = 0; i < 4; ++i) {
            float4 v0 = e[i * 4 + 0];
            float4 v1 = e[i * 4 + 1];
            float4 v2 = e[i * 4 + 2];
            float4 v3 = e[i * 4 + 3];
            FMA4(a0, i * 16 + 0,  v0)
            FMA4(a1, i * 16 + 4,  v1)
            FMA4(a2, i * 16 + 8,  v2)
            FMA4(a3, i * 16 + 12, v3)
        }
        float dot = (a0 + a1) + (a2 + a3);
        // replicate reference op order exactly (fp32, no contraction):
        //   t = fl(znorm + cnorm[k]);  u = fl(2*dot);  d = fl(t - u)
        float t = znorm + cnorm[k];
        float u = 2.0f * dot;
        float dist = t - u;
        if (dist < best) { best = dist; bestk = k; }  // strict <: lowest k on tie
    }

    // combine the 4 waves' candidates (ascending k-range order => np tiebreak)
    __shared__ float sval[4][64];
    __shared__ int   sidx[4][64];
    __shared__ int   sfin[64];
    sval[wid][lane] = best;
    sidx[wid][lane] = bestk;
    __syncthreads();
    if (tid < 64) {
        float bv = sval[0][tid];
        int   bi = sidx[0][tid];
#pragma unroll
        for (int w = 1; w < 4; ++w) {
            float v  = sval[w][tid];
            int   i2 = sidx[w][tid];
            if (v < bv) { bv = v; bi = i2; }
        }
        sfin[tid] = bi;
        out[n0 + tid] = (float)bi;     // zis as float
    }
    __syncthreads();

    // gather chosen codebook rows into LDS tile [pos][chan] (pad 65: 2-way free)
    __shared__ float tile[64][65];
    {
        const int p = tid >> 2, q = tid & 3;
        const int idx = sfin[p];
        const float4* row = cb4 + idx * (CDIM / 4) + q * 4;
#pragma unroll
        for (int i = 0; i < 4; ++i) {
            float4 v = row[i];
            const int c = q * 16 + i * 4;
            tile[p][c + 0] = v.x; tile[p][c + 1] = v.y;
            tile[p][c + 2] = v.z; tile[p][c + 3] = v.w;
        }
    }
    __syncthreads();

    // coalesced BCHW writes: wave w writes channels c = i*4 + w
    float* zq = out + NPOS + ((b * CDIM) << 12) + hw0;
#pragma unroll
    for (int i = 0; i < 16; ++i) {
        const int c = i * 4 + wid;
        zq[(c << 12) + lane] = tile[lane][c];
    }
}

extern "C" void kernel_launch(void* const* d_in, const int* in_sizes, int n_in,
                              void* d_out, int out_size, void* d_ws, size_t ws_size,
                              hipStream_t stream) {
    const float* in = (const float*)d_in[0];   // 16*64*64*64
    const float* cb = (const float*)d_in[1];   // 1024*64
    float* out   = (float*)d_out;              // 65536 + 4194304
    float* cnorm = (float*)d_ws;               // 1024 floats scratch

    vq_cnorm_kernel<<<NUM_K / 256, 256, 0, stream>>>(cb, cnorm);
    vq_main_kernel<<<NPOS / 64, 256, 0, stream>>>(in, cb, cnorm, out);
}

// Round 3
// 135.622 us; speedup vs baseline: 3.5565x; 3.5565x over previous
//
#include <hip/hip_runtime.h>

// VQ: inputs (16,64,64,64) f32 BCHW, codebook (1024,64) f32.
// out[0:65536]        = argmin indices as float
// out[65536: +4.19M]  = gathered codebook vectors, BCHW layout
//
// Numerics (verified r2, absmax=0): replicate numpy's fp32 formula where it
// matters: (a) znorm BIT-EXACT pairwise (8 accumulators + tree, contract off),
// (b) per-(n,k): t=fl(znorm+cnorm[k]); u=fl(2*dot); d=fl(t-u). The dot's
// fp32 accumulation order perturbs d by ~1e-10 vs the 7.6e-6 ulp(64) grid ->
// negligible flip probability. Tie-break: lexicographic (value, index) min.
//
// r3 structure: LDS-tiled register-blocked VALU GEMM (no fp32 MFMA on CDNA4).
// Block = 64 positions x 1024 codes; 256 thr = 16 n-thr x 16 k-thr; per-thread
// 4x8 accumulator tile; zT[c][n] + eT[c][k] in LDS; 3 ds_read_b128 / 32 fmaf.
#define NUM_K 1024
#define CDIM  64
#define NPOS  65536     // 16*64*64
#define KC    128       // codes per chunk
#define NCHUNK (NUM_K / KC)

// ---- kernel 1: codebook squared norms into d_ws (1024 floats) ----
__global__ __launch_bounds__(256) void vq_cnorm_kernel(
    const float* __restrict__ cb, float* __restrict__ cnorm) {
#pragma clang fp contract(off)
    int k = blockIdx.x * 256 + threadIdx.x;   // grid = 4 blocks
    const float* row = cb + k * CDIM;
    float r[8];
#pragma unroll
    for (int j = 0; j < 8; ++j) r[j] = row[j] * row[j];
#pragma unroll
    for (int i = 1; i < 8; ++i) {
#pragma unroll
        for (int j = 0; j < 8; ++j) {
            float s = row[i * 8 + j] * row[i * 8 + j];
            r[j] = r[j] + s;
        }
    }
    cnorm[k] = ((r[0] + r[1]) + (r[2] + r[3])) + ((r[4] + r[5]) + (r[6] + r[7]));
}

// ---- kernel 2: main VQ ----
__global__ __launch_bounds__(256, 3) void vq_main_kernel(
    const float* __restrict__ in, const float* __restrict__ cb,
    const float* __restrict__ cnorm, float* __restrict__ out) {
#pragma clang fp contract(off)
    const int tid = threadIdx.x;
    const int n0g = blockIdx.x << 6;
    const int b   = n0g >> 12;       // batch image (64 | 4096 so no straddle)
    const int hw0 = n0g & 4095;

    __shared__ float zT[CDIM][64];   // [c][n]   16 KB (reused for argmin reduce)
    __shared__ float eT[CDIM][KC];   // [c][k]   32 KB (reused for output tile)
    __shared__ float znormS[64];
    __shared__ int   sfin[64];

    // ---- stage zT (coalesced: lanes sweep n for fixed c) ----
    {
        const int n  = tid & 63;
        const int cg = tid >> 6;                 // 4 c-groups of 16
        const float* zp = in + (((size_t)b * CDIM) << 12) + hw0 + n;
#pragma unroll
        for (int i = 0; i < 16; ++i) {
            const int c = cg * 16 + i;
            zT[c][n] = zp[(size_t)c << 12];
        }
    }
    __syncthreads();

    // ---- znorm: bit-exact numpy pairwise sum of squares (threads 0..63) ----
    if (tid < 64) {
        float r[8];
#pragma unroll
        for (int j = 0; j < 8; ++j) { float v = zT[j][tid]; r[j] = v * v; }
#pragma unroll
        for (int i = 1; i < 8; ++i) {
#pragma unroll
            for (int j = 0; j < 8; ++j) {
                float v = zT[i * 8 + j][tid];
                float s = v * v;
                r[j] = r[j] + s;
            }
        }
        znormS[tid] =
            ((r[0] + r[1]) + (r[2] + r[3])) + ((r[4] + r[5]) + (r[6] + r[7]));
    }
    __syncthreads();

    const int nth = tid & 15;        // n-thread 0..15
    const int kth = tid >> 4;        // k-thread 0..15
    const int n0  = nth * 4;
    const int k0  = kth * 8;

    float zn[4];
#pragma unroll
    for (int n = 0; n < 4; ++n) zn[n] = znormS[n0 + n];

    float best[4] = {3.4e38f, 3.4e38f, 3.4e38f, 3.4e38f};
    int   bk[4]   = {0, 0, 0, 0};

    const float4* cb4 = reinterpret_cast<const float4*>(cb);

    for (int ch = 0; ch < NCHUNK; ++ch) {
        const int kc0 = ch * KC;

        // ---- stage eT[c][k] for this chunk (transpose from row-major cb) ----
        // thread t: code k = t>>1, c-half = (t&1)*32 -> 8 float4 loads,
        // 32 ds_write_b32 (2 lanes/bank = free)
        {
            const int k  = tid >> 1;
            const int c0 = (tid & 1) * 32;
            const float4* src = cb4 + (size_t)(kc0 + k) * (CDIM / 4) + (c0 >> 2);
#pragma unroll
            for (int i = 0; i < 8; ++i) {
                float4 v = src[i];
                const int c = c0 + i * 4;
                eT[c + 0][k] = v.x; eT[c + 1][k] = v.y;
                eT[c + 2][k] = v.z; eT[c + 3][k] = v.w;
            }
        }
        __syncthreads();

        // ---- register-tiled dot products: acc[n][i] over c ----
        float acc[4][8];
#pragma unroll
        for (int n = 0; n < 4; ++n)
#pragma unroll
            for (int i = 0; i < 8; ++i) acc[n][i] = 0.0f;

#pragma unroll 8
        for (int c = 0; c < CDIM; ++c) {
            const float4 zf = *reinterpret_cast<const float4*>(&zT[c][n0]);
            const float4 e0 = *reinterpret_cast<const float4*>(&eT[c][k0]);
            const float4 e1 = *reinterpret_cast<const float4*>(&eT[c][k0 + 4]);
            const float zv[4] = {zf.x, zf.y, zf.z, zf.w};
            const float ev[8] = {e0.x, e0.y, e0.z, e0.w, e1.x, e1.y, e1.z, e1.w};
#pragma unroll
            for (int n = 0; n < 4; ++n)
#pragma unroll
                for (int i = 0; i < 8; ++i)
                    acc[n][i] = fmaf(zv[n], ev[i], acc[n][i]);
        }

        // ---- scores + running argmin (k ascending within thread) ----
        const float4 cn0 = *reinterpret_cast<const float4*>(&cnorm[kc0 + k0]);
        const float4 cn1 = *reinterpret_cast<const float4*>(&cnorm[kc0 + k0 + 4]);
        const float cns[8] = {cn0.x, cn0.y, cn0.z, cn0.w,
                              cn1.x, cn1.y, cn1.z, cn1.w};
#pragma unroll
        for (int i = 0; i < 8; ++i) {
            const int k = kc0 + k0 + i;
#pragma unroll
            for (int n = 0; n < 4; ++n) {
                float t = zn[n] + cns[i];      // fl(znorm + cnorm)
                float u = 2.0f * acc[n][i];    // fl(2*dot)
                float d = t - u;               // fl(t - u)
                if (d < best[n]) { best[n] = d; bk[n] = k; }
            }
        }
        __syncthreads();   // eT dead; safe to restage next chunk
    }

    // ---- cross-thread argmin: candidates rv/ri[n][j] overlaid on zT ----
    float* rv = &zT[0][0];               // 64*16 floats
    int*   ri = reinterpret_cast<int*>(&zT[16][0]);
#pragma unroll
    for (int n = 0; n < 4; ++n) {
        rv[(n0 + n) * 16 + kth] = best[n];
        ri[(n0 + n) * 16 + kth] = bk[n];
    }
    __syncthreads();
    if (tid < 64) {
        float bv = rv[tid * 16];
        int   bi = ri[tid * 16];
#pragma unroll
        for (int j = 1; j < 16; ++j) {
            float v  = rv[tid * 16 + j];
            int   ii = ri[tid * 16 + j];
            if (v < bv || (v == bv && ii < bi)) { bv = v; bi = ii; }
        }
        sfin[tid] = bi;
        out[n0g + tid] = (float)bi;      // zis as float
    }
    __syncthreads();

    // ---- gather chosen rows into tile[pos][chan] (overlaid on eT) ----
    float (*tile)[65] = reinterpret_cast<float(*)[65]>(&eT[0][0]);
    {
        const int p = tid >> 2, q = tid & 3;
        const int idx = sfin[p];
        const float4* row = cb4 + (size_t)idx * (CDIM / 4) + q * 4;
#pragma unroll
        for (int i = 0; i < 4; ++i) {
            float4 v = row[i];
            const int c = q * 16 + i * 4;
            tile[p][c + 0] = v.x; tile[p][c + 1] = v.y;
            tile[p][c + 2] = v.z; tile[p][c + 3] = v.w;
        }
    }
    __syncthreads();

    // ---- coalesced BCHW writes: wave w writes channels c = i*4 + w ----
    {
        const int lane = tid & 63, wid = tid >> 6;
        float* zq = out + NPOS + (((size_t)b * CDIM) << 12) + hw0;
#pragma unroll
        for (int i = 0; i < 16; ++i) {
            const int c = i * 4 + wid;
            zq[((size_t)c << 12) + lane] = tile[lane][c];
        }
    }
}

extern "C" void kernel_launch(void* const* d_in, const int* in_sizes, int n_in,
                              void* d_out, int out_size, void* d_ws, size_t ws_size,
                              hipStream_t stream) {
    const float* in = (const float*)d_in[0];   // 16*64*64*64
    const float* cb = (const float*)d_in[1];   // 1024*64
    float* out   = (float*)d_out;              // 65536 + 4194304
    float* cnorm = (float*)d_ws;               // 1024 floats scratch

    vq_cnorm_kernel<<<NUM_K / 256, 256, 0, stream>>>(cb, cnorm);
    vq_main_kernel<<<NPOS / 64, 256, 0, stream>>>(in, cb, cnorm, out);
}

// Round 4
// 127.309 us; speedup vs baseline: 3.7887x; 1.0653x over previous
//
#include <hip/hip_runtime.h>
#include <stdint.h>

// VQ: inputs (16,64,64,64) f32 BCHW, codebook (1024,64) f32.
// out[0:65536] = argmin indices as float; out[65536:] = gathered rows, BCHW.
//
// r4: bf16-split (hi+lo) 3-pass MFMA filter + exact in-block rescreen.
//  - filter: s~ = (cnorm+0.125) - 2*dot~, dot~ from mfma_f32_16x16x32_bf16
//    accumulating hh+hl+lh passes in fp32. Error <= ~1e-6.
//  - pack: key = (bits(s~) & ~1023) | k  -> fmin tracks argmin with
//    first-occurrence tiebreak; (m1,m2) give a gap lower-bound.
//  - gap < DELTA (8e-5, covers split err + pack quant 4e-6 + ref's
//    ulp(64)=7.6e-6 d-grid)  -> exact rescreen with r3's validated
//    numerics (bit-exact pairwise znorm, t=fl(zn+cn); u=fl(2dot); d=fl(t-u)).
//  - fragment staging: BOTH operands stored [row][k-contiguous]; any
//    intra-lane k-permutation cancels in the contraction (m97 pattern).
#define NUM_K 1024
#define CDIM  64
#define NPOS  65536
#define NPB   128       // positions per block
#define KC    64        // codes per chunk
#define NCH   (NUM_K / KC)
#define DELTA 8e-5f

typedef __attribute__((ext_vector_type(8))) short short8;
typedef __attribute__((ext_vector_type(4))) float f32x4;

// ---- kernel 1: exact codebook squared norms (numpy pairwise) ----
__global__ __launch_bounds__(256) void vq_cnorm_kernel(
    const float* __restrict__ cb, float* __restrict__ cnorm) {
#pragma clang fp contract(off)
    int k = blockIdx.x * 256 + threadIdx.x;
    const float* row = cb + k * CDIM;
    float r[8];
#pragma unroll
    for (int j = 0; j < 8; ++j) r[j] = row[j] * row[j];
#pragma unroll
    for (int i = 1; i < 8; ++i) {
#pragma unroll
        for (int j = 0; j < 8; ++j) {
            float s = row[i * 8 + j] * row[i * 8 + j];
            r[j] = r[j] + s;
        }
    }
    cnorm[k] = ((r[0] + r[1]) + (r[2] + r[3])) + ((r[4] + r[5]) + (r[6] + r[7]));
}

// f32 pair -> packed bf16 pair (RNE) for hi, and packed bf16 of residual (lo)
__device__ __forceinline__ void cvt_pair(float f0, float f1,
                                         uint32_t& hp, uint32_t& lp) {
    uint32_t h;
    asm("v_cvt_pk_bf16_f32 %0, %1, %2" : "=v"(h) : "v"(f0), "v"(f1));
    float h0 = __uint_as_float(h << 16);
    float h1 = __uint_as_float(h & 0xFFFF0000u);
    float r0 = f0 - h0, r1 = f1 - h1;
    uint32_t l;
    asm("v_cvt_pk_bf16_f32 %0, %1, %2" : "=v"(l) : "v"(r0), "v"(r1));
    hp = h; lp = l;
}

__device__ __forceinline__ unsigned long long shflxor64(unsigned long long v, int off) {
    unsigned lo = (unsigned)v, hi = (unsigned)(v >> 32);
    lo = (unsigned)__shfl_xor((int)lo, off);
    hi = (unsigned)__shfl_xor((int)hi, off);
    return ((unsigned long long)hi << 32) | lo;
}

#define RFMA4(acc, zb, v)                          \
    acc = fmaf(zsc[(zb) + 0], v.x, acc);           \
    acc = fmaf(zsc[(zb) + 1], v.y, acc);           \
    acc = fmaf(zsc[(zb) + 2], v.z, acc);           \
    acc = fmaf(zsc[(zb) + 3], v.w, acc);

// LDS map (bytes)
#define OFF_ZHI   0        // 128 rows * 128B (bf16 hi, k-contig, xor-swizzled)
#define OFF_ZLO   16384
#define OFF_CBHI  32768    // 64 rows * 128B
#define OFF_CBLO  40960
#define OFF_CNB   49152    // 1024 f32 (cnorm + 0.125)
#define OFF_SFIN  53248    // 128 int
#define OFF_AMBC  53760
#define OFF_AMBL  53792    // 128 int
#define OFF_ZSC   54304    // 64 f32 (rescreen z row)
#define OFF_ZN    54560
#define OFF_WRED  54568    // 4 u64
#define SMEM_SZ   54600

__global__ __launch_bounds__(256, 2) void vq_main_kernel(
    const float* __restrict__ in, const float* __restrict__ cb,
    const float* __restrict__ cnorm, float* __restrict__ out) {
#pragma clang fp contract(off)
    const int tid  = threadIdx.x;
    const int lane = tid & 63;
    const int wv   = tid >> 6;
    const int n0g  = blockIdx.x * NPB;
    const int b    = n0g >> 12;
    const int hw0  = n0g & 4095;

    __shared__ __align__(16) unsigned char smem[SMEM_SZ];
    unsigned char* zhi_  = smem + OFF_ZHI;
    unsigned char* zlo_  = smem + OFF_ZLO;
    unsigned char* cbhi_ = smem + OFF_CBHI;
    unsigned char* cblo_ = smem + OFF_CBLO;
    float* cnb     = (float*)(smem + OFF_CNB);
    int*   sfin    = (int*)(smem + OFF_SFIN);
    int*   ambcnt  = (int*)(smem + OFF_AMBC);
    int*   amblist = (int*)(smem + OFF_AMBL);
    float* zsc     = (float*)(smem + OFF_ZSC);
    float* znsc    = (float*)(smem + OFF_ZN);
    unsigned long long* wred = (unsigned long long*)(smem + OFF_WRED);

    if (tid == 0) *ambcnt = 0;

    // ---- stage cnb = cnorm + bias ----
#pragma unroll
    for (int i = 0; i < 4; ++i) cnb[i * 256 + tid] = cnorm[i * 256 + tid] + 0.125f;

    // ---- stage z as bf16 hi/lo, [n][c-contig], row-xor-swizzled ----
    {
        const int n  = tid & 127;
        const int ch = tid >> 7;
        const float* zp = in + (((size_t)b * CDIM) << 12) + hw0 + n;
#pragma unroll
        for (int s = 0; s < 4; ++s) {
            float f[8];
#pragma unroll
            for (int j = 0; j < 8; ++j)
                f[j] = zp[(size_t)(ch * 32 + s * 8 + j) << 12];
            uint32_t hp[4], lp[4];
#pragma unroll
            for (int p = 0; p < 4; ++p) cvt_pair(f[2 * p], f[2 * p + 1], hp[p], lp[p]);
            const int byte = n * 128 + (((ch * 4 + s) * 16) ^ ((n & 7) * 16));
            uint4 hv; hv.x = hp[0]; hv.y = hp[1]; hv.z = hp[2]; hv.w = hp[3];
            uint4 lv; lv.x = lp[0]; lv.y = lp[1]; lv.z = lp[2]; lv.w = lp[3];
            *(uint4*)(zhi_ + byte) = hv;
            *(uint4*)(zlo_ + byte) = lv;
        }
    }
    __syncthreads();

    // ---- preload this wave's z fragments (B operand), 32 n per wave ----
    short8 zf[2][2][2];  // [nset][Kstep][hi/lo]
    {
        const int wb = wv * 32;
#pragma unroll
        for (int ns = 0; ns < 2; ++ns)
#pragma unroll
            for (int ks = 0; ks < 2; ++ks) {
                const int n = wb + ns * 16 + (lane & 15);
                const int slot = ks * 4 + (lane >> 4);
                const int byte = n * 128 + ((slot * 16) ^ ((n & 7) * 16));
                zf[ns][ks][0] = *(const short8*)(zhi_ + byte);
                zf[ns][ks][1] = *(const short8*)(zlo_ + byte);
            }
    }

    const int kloc = tid >> 3;   // 0..31
    const int oct  = tid & 7;
    const float4* cb4 = (const float4*)cb;

    float4 pf[4];
    {   // prefetch chunk 0
        const int k0 = kloc, k1 = kloc + 32;
        pf[0] = cb4[(size_t)k0 * 16 + oct * 2];
        pf[1] = cb4[(size_t)k0 * 16 + oct * 2 + 1];
        pf[2] = cb4[(size_t)k1 * 16 + oct * 2];
        pf[3] = cb4[(size_t)k1 * 16 + oct * 2 + 1];
    }

    const float finf = __uint_as_float(0x7F800000u);
    float m1[2] = {finf, finf}, m2[2] = {finf, finf};

    for (int ch = 0; ch < NCH; ++ch) {
        // ---- write prefetched chunk to LDS (hi/lo, row-swizzled) ----
#pragma unroll
        for (int half = 0; half < 2; ++half) {
            const int kr = kloc + half * 32;
            float4 a = pf[half * 2], c2 = pf[half * 2 + 1];
            float f[8] = {a.x, a.y, a.z, a.w, c2.x, c2.y, c2.z, c2.w};
            uint32_t hp[4], lp[4];
#pragma unroll
            for (int p = 0; p < 4; ++p) cvt_pair(f[2 * p], f[2 * p + 1], hp[p], lp[p]);
            const int byte = kr * 128 + ((oct * 16) ^ ((kr & 7) * 16));
            uint4 hv; hv.x = hp[0]; hv.y = hp[1]; hv.z = hp[2]; hv.w = hp[3];
            uint4 lv; lv.x = lp[0]; lv.y = lp[1]; lv.z = lp[2]; lv.w = lp[3];
            *(uint4*)(cbhi_ + byte) = hv;
            *(uint4*)(cblo_ + byte) = lv;
        }
        __syncthreads();

        if (ch < NCH - 1) {  // prefetch next chunk (hidden under MFMA)
            const size_t base = (size_t)(ch + 1) * KC;
            pf[0] = cb4[(base + kloc) * 16 + oct * 2];
            pf[1] = cb4[(base + kloc) * 16 + oct * 2 + 1];
            pf[2] = cb4[(base + kloc + 32) * 16 + oct * 2];
            pf[3] = cb4[(base + kloc + 32) * 16 + oct * 2 + 1];
        }

        const int kc0 = ch * KC;
#pragma unroll
        for (int kt = 0; kt < 4; ++kt) {
            short8 af[2][2];  // [Kstep][hi/lo]
            const int kr = kt * 16 + (lane & 15);
#pragma unroll
            for (int ks = 0; ks < 2; ++ks) {
                const int slot = ks * 4 + (lane >> 4);
                const int byte = kr * 128 + ((slot * 16) ^ ((kr & 7) * 16));
                af[ks][0] = *(const short8*)(cbhi_ + byte);
                af[ks][1] = *(const short8*)(cblo_ + byte);
            }
            const int kbase = kc0 + kt * 16 + ((lane >> 4) << 2);
            float cn[4];
#pragma unroll
            for (int r = 0; r < 4; ++r) cn[r] = cnb[kbase + r];

#pragma unroll
            for (int nt = 0; nt < 2; ++nt) {
                f32x4 acc = {0.f, 0.f, 0.f, 0.f};
                acc = __builtin_amdgcn_mfma_f32_16x16x32_bf16(af[0][1], zf[nt][0][0], acc, 0, 0, 0);
                acc = __builtin_amdgcn_mfma_f32_16x16x32_bf16(af[0][0], zf[nt][0][1], acc, 0, 0, 0);
                acc = __builtin_amdgcn_mfma_f32_16x16x32_bf16(af[0][0], zf[nt][0][0], acc, 0, 0, 0);
                acc = __builtin_amdgcn_mfma_f32_16x16x32_bf16(af[1][1], zf[nt][1][0], acc, 0, 0, 0);
                acc = __builtin_amdgcn_mfma_f32_16x16x32_bf16(af[1][0], zf[nt][1][1], acc, 0, 0, 0);
                acc = __builtin_amdgcn_mfma_f32_16x16x32_bf16(af[1][0], zf[nt][1][0], acc, 0, 0, 0);
#pragma unroll
                for (int r = 0; r < 4; ++r) {
                    float s = fmaf(-2.0f, acc[r], cn[r]);
                    float key = __uint_as_float(
                        (__float_as_uint(s) & 0xFFFFFC00u) | (uint32_t)(kbase + r));
                    float mx = fmaxf(key, m1[nt]);
                    m2[nt] = fminf(m2[nt], mx);
                    m1[nt] = fminf(m1[nt], key);
                }
            }
        }
        __syncthreads();
    }

    // ---- cross-lane combine (lanes n, n+16, n+32, n+48 share a position) ----
#pragma unroll
    for (int nt = 0; nt < 2; ++nt) {
#pragma unroll
        for (int off = 16; off <= 32; off <<= 1) {
            float o1 = __shfl_xor(m1[nt], off);
            float o2 = __shfl_xor(m2[nt], off);
            m2[nt] = fminf(fminf(m2[nt], o2), fmaxf(m1[nt], o1));
            m1[nt] = fminf(m1[nt], o1);
        }
    }

    if ((lane & 48) == 0) {  // lane < 16
#pragma unroll
        for (int nt = 0; nt < 2; ++nt) {
            const int nl = wv * 32 + nt * 16 + lane;
            const uint32_t u1 = __float_as_uint(m1[nt]);
            const int idx = (int)(u1 & 1023u);
            const float v1 = __uint_as_float(u1 & 0xFFFFFC00u);
            const float v2 = __uint_as_float(__float_as_uint(m2[nt]) & 0xFFFFFC00u);
            sfin[nl] = idx;
            out[n0g + nl] = (float)idx;
            if (v2 - v1 < DELTA) {
                int p = atomicAdd(ambcnt, 1);
                amblist[p] = nl;
            }
        }
    }
    __syncthreads();

    // ---- exact rescreen of ambiguous positions (r3-validated numerics) ----
    const int namb = *ambcnt;
    for (int i = 0; i < namb; ++i) {
        const int n = amblist[i];
        if (tid < 64)
            zsc[tid] = in[(((size_t)(b * CDIM + tid)) << 12) + hw0 + n];
        __syncthreads();
        if (tid == 0) {  // bit-exact numpy pairwise znorm
            float rr[8];
#pragma unroll
            for (int j = 0; j < 8; ++j) rr[j] = zsc[j] * zsc[j];
#pragma unroll
            for (int i2 = 1; i2 < 8; ++i2) {
#pragma unroll
                for (int j = 0; j < 8; ++j) {
                    float s2 = zsc[i2 * 8 + j] * zsc[i2 * 8 + j];
                    rr[j] = rr[j] + s2;
                }
            }
            *znsc = ((rr[0] + rr[1]) + (rr[2] + rr[3])) + ((rr[4] + rr[5]) + (rr[6] + rr[7]));
        }
        __syncthreads();
        const float zn = *znsc;
        unsigned long long bestk = ~0ull;
#pragma unroll
        for (int j = 0; j < 4; ++j) {
            const int k = tid * 4 + j;
            const float4* e = cb4 + (size_t)k * 16;
            float a0 = 0.f, a1 = 0.f, a2 = 0.f, a3 = 0.f;
#pragma unroll
            for (int i2 = 0; i2 < 4; ++i2) {
                float4 v0 = e[i2 * 4 + 0];
                float4 v1 = e[i2 * 4 + 1];
                float4 v2 = e[i2 * 4 + 2];
                float4 v3 = e[i2 * 4 + 3];
                RFMA4(a0, i2 * 16 + 0,  v0)
                RFMA4(a1, i2 * 16 + 4,  v1)
                RFMA4(a2, i2 * 16 + 8,  v2)
                RFMA4(a3, i2 * 16 + 12, v3)
            }
            float dot = (a0 + a1) + (a2 + a3);
            float t = zn + cnorm[k];
            float u = 2.0f * dot;
            float d = t - u;
            unsigned long long key =
                ((unsigned long long)__float_as_uint(d) << 10) | (unsigned)k;
            bestk = key < bestk ? key : bestk;
        }
#pragma unroll
        for (int off = 32; off >= 1; off >>= 1) {
            unsigned long long o = shflxor64(bestk, off);
            bestk = o < bestk ? o : bestk;
        }
        if (lane == 0) wred[wv] = bestk;
        __syncthreads();
        if (tid == 0) {
            unsigned long long bk = wred[0];
#pragma unroll
            for (int w = 1; w < 4; ++w) bk = wred[w] < bk ? wred[w] : bk;
            const int idx = (int)(bk & 1023u);
            sfin[n] = idx;
            out[n0g + n] = (float)idx;
        }
        __syncthreads();
    }

    // ---- zqs: gather rows -> LDS tile (overlay on z region) -> BCHW writes ----
    float (*tile)[65] = (float (*)[65])(smem);
    for (int h = 0; h < 2; ++h) {
        __syncthreads();
        {
            const int p = tid >> 2, q = tid & 3;
            const int idx = sfin[h * 64 + p];
            const float4* row = cb4 + (size_t)idx * 16 + q * 4;
#pragma unroll
            for (int i = 0; i < 4; ++i) {
                float4 v = row[i];
                const int c = q * 16 + i * 4;
                tile[p][c + 0] = v.x; tile[p][c + 1] = v.y;
                tile[p][c + 2] = v.z; tile[p][c + 3] = v.w;
            }
        }
        __syncthreads();
        float* zq = out + NPOS + (((size_t)b * CDIM) << 12) + hw0 + h * 64;
#pragma unroll
        for (int i = 0; i < 16; ++i) {
            const int c = i * 4 + wv;
            zq[((size_t)c << 12) + lane] = tile[lane][c];
        }
    }
}

extern "C" void kernel_launch(void* const* d_in, const int* in_sizes, int n_in,
                              void* d_out, int out_size, void* d_ws, size_t ws_size,
                              hipStream_t stream) {
    const float* in = (const float*)d_in[0];   // 16*64*64*64
    const float* cb = (const float*)d_in[1];   // 1024*64
    float* out   = (float*)d_out;              // 65536 + 4194304
    float* cnorm = (float*)d_ws;               // 1024 floats scratch

    vq_cnorm_kernel<<<NUM_K / 256, 256, 0, stream>>>(cb, cnorm);
    vq_main_kernel<<<NPOS / NPB, 256, 0, stream>>>(in, cb, cnorm, out);
}